// Round 2
// baseline (262.628 us; speedup 1.0000x reference)
//
#include <hip/hip_runtime.h>
#include <hip/hip_cooperative_groups.h>
namespace cg = cooperative_groups;

#define NP 16384
#define NS 8192
#define DP 256
#define DS 128
#define DI 128
#define GRID 512
#define BLK 256
#define NWAVES (GRID*(BLK/64))

// ws float offsets
#define WSUM_P 0
#define WSUM_S 256
#define BSUMS  384
#define R_P    512
#define R_S    (R_P+NP)
#define CH_MP  (R_S+NS)
#define CH_ZP  (CH_MP+GRID)
#define CH_MS  (CH_ZP+GRID)
#define CH_ZS  (CH_MS+GRID)
#define PART_P (CH_ZS+GRID)
#define PART_S (PART_P+GRID*DP)
#define U_P    (PART_S+GRID*DS)
#define U_S    (U_P+DP)

// out float offsets
#define O1 (NP*DP)
#define O2 (O1+NP)
#define O3 (O2+NS*DS)
#define TOTAL (O3+NS)
#define TOTAL4 (TOTAL/4)

__device__ __forceinline__ float wsum64(float s) {
    #pragma unroll
    for (int m = 32; m >= 1; m >>= 1) s += __shfl_xor(s, m, 64);
    return s;
}

__global__ __launch_bounds__(BLK, 2)
void fused(const float* __restrict__ pn, const float* __restrict__ sn,
           const float* __restrict__ Wpp, const float* __restrict__ bpp,
           const float* __restrict__ Wsp, const float* __restrict__ bsp,
           const float* __restrict__ Wpo, const float* __restrict__ bpo,
           const float* __restrict__ Wso, const float* __restrict__ bso,
           const int* __restrict__ pidx, const int* __restrict__ sidx,
           float* __restrict__ ws, float* __restrict__ out) {
    cg::grid_group grid = cg::this_grid();
    __shared__ float sh[1216];
    const int t = threadIdx.x;
    const int lane = t & 63;
    const int gw = blockIdx.x * (BLK/64) + (t >> 6);

    // ---- P0: column sums of W_*_proj + bias sums (one wave per output) ----
    if (gw < 256) {
        float s = wsum64(Wpp[gw*DI + lane] + Wpp[gw*DI + 64 + lane]);
        if (lane == 0) ws[WSUM_P + gw] = s;
    } else if (gw < 384) {
        const int c = gw - 256;
        float s = wsum64(Wsp[c*DI + lane] + Wsp[c*DI + 64 + lane]);
        if (lane == 0) ws[WSUM_S + c] = s;
    } else if (gw == 384) {
        float s = wsum64(bpp[lane] + bpp[64+lane]);
        if (lane == 0) ws[BSUMS+0] = s;
    } else if (gw == 385) {
        float s = wsum64(bsp[lane] + bsp[64+lane]);
        if (lane == 0) ws[BSUMS+1] = s;
    }
    grid.sync();

    // ---- P1: row sums r_p, r_s (wave per row, grid-stride) ----
    {
        const float4 wp  = *(const float4*)(ws + WSUM_P + lane*4);
        const float2 wsv = *(const float2*)(ws + WSUM_S + lane*2);
        const float bp = ws[BSUMS+0], bs = ws[BSUMS+1];
        for (int row = gw; row < NP+NS; row += NWAVES) {
            if (row < NP) {
                const float4 x = *(const float4*)(pn + (size_t)row*DP + lane*4);
                float s = wsum64(x.x*wp.x + x.y*wp.y + x.z*wp.z + x.w*wp.w);
                if (lane == 0) ws[R_P + row] = s + bp;
            } else {
                const int r2 = row - NP;
                const float2 x = *(const float2*)(sn + (size_t)r2*DS + lane*2);
                float s = wsum64(x.x*wsv.x + x.y*wsv.y);
                if (lane == 0) ws[R_S + r2] = s + bs;
            }
        }
    }
    grid.sync();

    // ---- P2: per-chunk local-max softmax partials (flash-style) ----
    {
        const int b = blockIdx.x;
        if (t < 64) {          // wave 0: prot chunk weights (32 rows)
            float r = (lane < 32) ? ws[R_P + pidx[b*32 + lane]] : -INFINITY;
            float m = r;
            #pragma unroll
            for (int o = 16; o >= 1; o >>= 1) m = fmaxf(m, __shfl_xor(m, o, 64));
            float w = (lane < 32) ? expf(r - m) : 0.f;
            float z = w;
            #pragma unroll
            for (int o = 16; o >= 1; o >>= 1) z += __shfl_xor(z, o, 64);
            if (lane < 32) sh[lane] = w;
            if (lane == 0) { ws[CH_MP+b] = m; ws[CH_ZP+b] = z; }
        } else if (t < 128) {  // wave 1: sub chunk weights (16 rows)
            float r = (lane < 16) ? ws[R_S + sidx[b*16 + lane]] : -INFINITY;
            float m = r;
            #pragma unroll
            for (int o = 8; o >= 1; o >>= 1) m = fmaxf(m, __shfl_xor(m, o, 64));
            float w = (lane < 16) ? expf(r - m) : 0.f;
            float z = w;
            #pragma unroll
            for (int o = 8; o >= 1; o >>= 1) z += __shfl_xor(z, o, 64);
            if (lane < 16) sh[32 + lane] = w;
            if (lane == 0) { ws[CH_MS+b] = m; ws[CH_ZS+b] = z; }
        }
        __syncthreads();
        {
            float acc = 0.f;
            const float* base = pn + (size_t)b*32*DP + t;
            #pragma unroll 8
            for (int k = 0; k < 32; ++k) acc += sh[k] * base[(size_t)k*DP];
            ws[PART_P + b*DP + t] = acc;
        }
        if (t < DS) {
            float acc = 0.f;
            const float* base = sn + (size_t)b*16*DS + t;
            #pragma unroll 8
            for (int k = 0; k < 16; ++k) acc += sh[32+k] * base[(size_t)k*DS];
            ws[PART_S + b*DS + t] = acc;
        }
    }
    grid.sync();

    // ---- P3: combine partials + tiny matvecs (2 independent chains) ----
    if (blockIdx.x < 2) {
        float* e   = sh;         // 512
        float* red = sh + 512;   // 256
        float* mv  = sh + 768;   // 256
        float* vv  = sh + 1024;  // 128
        const bool isP = (blockIdx.x == 0);
        const float* chM = ws + (isP ? CH_MP : CH_MS);
        const float* chZ = ws + (isP ? CH_ZP : CH_ZS);
        red[t] = fmaxf(chM[t], chM[t+256]); __syncthreads();
        for (int s = 128; s > 0; s >>= 1) { if (t < s) red[t] = fmaxf(red[t], red[t+s]); __syncthreads(); }
        const float M = red[0]; __syncthreads();
        red[t] = chZ[t]*expf(chM[t]-M) + chZ[t+256]*expf(chM[t+256]-M); __syncthreads();
        for (int s = 128; s > 0; s >>= 1) { if (t < s) red[t] += red[t+s]; __syncthreads(); }
        const float invZ = 1.f / red[0]; __syncthreads();
        e[t]     = expf(chM[t]-M)     * invZ;
        e[t+256] = expf(chM[t+256]-M) * invZ;
        __syncthreads();
        if (isP) {   // m_p -> v_p -> u_s
            float acc = 0.f;
            for (int b2 = 0; b2 < GRID; ++b2) acc += ws[PART_P + b2*DP + t] * e[b2];
            mv[t] = acc;
            __syncthreads();
            if (t < DI) {
                float s = bpp[t];
                for (int c = 0; c < DP; ++c) s += mv[c] * Wpp[c*DI + t];
                vv[t] = s;
            }
            __syncthreads();
            if (t < DS) {
                float s = bso[t];
                for (int d = 0; d < DI; ++d) s += vv[d] * Wso[d*DS + t];
                ws[U_S + t] = s;
            }
        } else {     // m_s -> v_s -> u_p
            if (t < DS) {
                float acc = 0.f;
                for (int b2 = 0; b2 < GRID; ++b2) acc += ws[PART_S + b2*DS + t] * e[b2];
                mv[t] = acc;
            }
            __syncthreads();
            if (t < DI) {
                float s = bsp[t];
                for (int c = 0; c < DS; ++c) s += mv[c] * Wsp[c*DI + t];
                vv[t] = s;
            }
            __syncthreads();
            float s = bpo[t];
            for (int d = 0; d < DI; ++d) s += vv[d] * Wpo[d*DP + t];
            ws[U_P + t] = s;
        }
    }
    grid.sync();

    // ---- P4: finalize all four outputs (float4 grid-stride) ----
    {
        sh[t] = ws[U_P + t];
        if (t < DS) sh[256 + t] = ws[U_S + t];
        __syncthreads();
        for (int g4 = blockIdx.x*BLK + t; g4 < TOTAL4; g4 += GRID*BLK) {
            const int e4 = g4 * 4;
            float4 o;
            if (e4 < O1) {
                float4 x = *(const float4*)(pn + e4);
                int c = e4 & (DP-1);
                o = make_float4(x.x + sh[c], x.y + sh[c+1], x.z + sh[c+2], x.w + sh[c+3]);
            } else if (e4 < O2) {
                int i = e4 - O1;
                int4 v = *(const int4*)(pidx + i);
                o = make_float4((float)v.x,(float)v.y,(float)v.z,(float)v.w);
            } else if (e4 < O3) {
                int i = e4 - O2;
                float4 x = *(const float4*)(sn + i);
                int c = i & (DS-1);
                o = make_float4(x.x + sh[256+c], x.y + sh[256+c+1], x.z + sh[256+c+2], x.w + sh[256+c+3]);
            } else {
                int i = e4 - O3;
                int4 v = *(const int4*)(sidx + i);
                o = make_float4((float)v.x,(float)v.y,(float)v.z,(float)v.w);
            }
            *(float4*)(out + e4) = o;
        }
    }
}

extern "C" void kernel_launch(void* const* d_in, const int* in_sizes, int n_in,
                              void* d_out, int out_size, void* d_ws, size_t ws_size,
                              hipStream_t stream) {
    const float* pn  = (const float*)d_in[0];
    const float* sn  = (const float*)d_in[1];
    const float* Wpp = (const float*)d_in[2];
    const float* bpp = (const float*)d_in[3];
    const float* Wsp = (const float*)d_in[4];
    const float* bsp = (const float*)d_in[5];
    const float* Wpo = (const float*)d_in[6];
    const float* bpo = (const float*)d_in[7];
    const float* Wso = (const float*)d_in[8];
    const float* bso = (const float*)d_in[9];
    const int* pidx  = (const int*)d_in[10];
    const int* sidx  = (const int*)d_in[11];
    float* ws  = (float*)d_ws;
    float* out = (float*)d_out;

    void* args[] = { (void*)&pn, (void*)&sn, (void*)&Wpp, (void*)&bpp,
                     (void*)&Wsp, (void*)&bsp, (void*)&Wpo, (void*)&bpo,
                     (void*)&Wso, (void*)&bso, (void*)&pidx, (void*)&sidx,
                     (void*)&ws, (void*)&out };
    hipLaunchCooperativeKernel((const void*)fused, dim3(GRID), dim3(BLK),
                               args, 0, stream);
}

// Round 3
// 55.748 us; speedup vs baseline: 4.7110x; 4.7110x over previous
//
#include <hip/hip_runtime.h>

#define NP 16384
#define NS 8192
#define DP 256
#define DS 128
#define DI 128

// ---- ws float offsets ----
#define R_P    0
#define R_S    NP
#define CH_MP  (R_S + NS)          // 256
#define CH_ZP  (CH_MP + 256)      // 256
#define CH_MS  (CH_ZP + 256)      // 128
#define CH_ZS  (CH_MS + 128)      // 128
#define PART_P (CH_ZS + 128)      // 256*DP
#define PART_S (PART_P + 256*DP)  // 128*DS
#define U_P    (PART_S + 128*DS)  // DP
#define U_S    (U_P + DP)         // DS

// ---- out float offsets ----
#define O1 (NP*DP)
#define O2 (O1 + NP)
#define O3 (O2 + NS*DS)
#define TOTAL (O3 + NS)
#define TOTAL4 (TOTAL/4)

#define GA    512     // kA grid: 384 prot blocks + 128 sub blocks
#define GA_P  384
#define NC_P  256     // prot chunks of 64 rows
#define NC_S  128     // sub chunks of 64 rows

__device__ __forceinline__ float wsum64(float s) {
    #pragma unroll
    for (int m = 32; m >= 1; m >>= 1) s += __shfl_xor(s, m, 64);
    return s;
}
__device__ __forceinline__ float wmax64(float s) {
    #pragma unroll
    for (int m = 32; m >= 1; m >>= 1) s = fmaxf(s, __shfl_xor(s, m, 64));
    return s;
}

// ---- kA: per-block weight-colsum preamble (LDS) + row sums ----
__global__ __launch_bounds__(256)
void kA(const float* __restrict__ pn, const float* __restrict__ sn,
        const float* __restrict__ Wpp, const float* __restrict__ bpp,
        const float* __restrict__ Wsp, const float* __restrict__ bsp,
        float* __restrict__ ws) {
    __shared__ float w[DP];
    __shared__ float bsumv;
    const int t = threadIdx.x;
    const int lane = t & 63;
    const int wv = t >> 6;
    if (blockIdx.x < GA_P) {
        // wsum_p[t] = sum_d Wpp[t*DI+d]
        {
            const float4* row = (const float4*)(Wpp + t * DI);
            float s = 0.f;
            #pragma unroll
            for (int d = 0; d < DI/4; ++d) { float4 v = row[d]; s += v.x + v.y + v.z + v.w; }
            w[t] = s;
        }
        if (t < 64) {
            float b = wsum64(bpp[t] + bpp[64 + t]);
            if (t == 0) bsumv = b;
        }
        __syncthreads();
        const float4 wp = *(const float4*)(w + lane * 4);
        const float bp = bsumv;
        const int nw = GA_P * 4;
        #pragma unroll 2
        for (int row = blockIdx.x * 4 + wv; row < NP; row += nw) {
            const float4 x = *(const float4*)(pn + (size_t)row * DP + lane * 4);
            float s = wsum64(x.x * wp.x + x.y * wp.y + x.z * wp.z + x.w * wp.w);
            if (lane == 0) ws[R_P + row] = s + bp;
        }
    } else {
        if (t < DS) {
            const float4* row = (const float4*)(Wsp + t * DI);
            float s = 0.f;
            #pragma unroll
            for (int d = 0; d < DI/4; ++d) { float4 v = row[d]; s += v.x + v.y + v.z + v.w; }
            w[t] = s;
        }
        if (t < 64) {
            float b = wsum64(bsp[t] + bsp[64 + t]);
            if (t == 0) bsumv = b;
        }
        __syncthreads();
        const float2 wsv = *(const float2*)(w + lane * 2);
        const float bs = bsumv;
        const int nw = (GA - GA_P) * 4;
        #pragma unroll 2
        for (int row = (blockIdx.x - GA_P) * 4 + wv; row < NS; row += nw) {
            const float2 x = *(const float2*)(sn + (size_t)row * DS + lane * 2);
            float s = wsum64(x.x * wsv.x + x.y * wsv.y);
            if (lane == 0) ws[R_S + row] = s + bs;
        }
    }
}

// ---- kB: flash-style per-chunk stats + weighted column partials ----
__global__ __launch_bounds__(256)
void kB(const float* __restrict__ pn, const float* __restrict__ sn,
        const int* __restrict__ pidx, const int* __restrict__ sidx,
        float* __restrict__ ws) {
    __shared__ float wgt[64];
    __shared__ float red[256];
    const int t = threadIdx.x;
    if (blockIdx.x < NC_P) {
        const int b = blockIdx.x;
        const int base = b * 64;
        if (t < 64) {
            const float r = ws[R_P + pidx[base + t]];
            const float m = wmax64(r);
            const float e = expf(r - m);
            const float z = wsum64(e);
            wgt[t] = e;
            if (t == 0) { ws[CH_MP + b] = m; ws[CH_ZP + b] = z; }
        }
        __syncthreads();
        float acc = 0.f;
        const float* basep = pn + (size_t)base * DP + t;
        #pragma unroll 8
        for (int k = 0; k < 64; ++k) acc += wgt[k] * basep[(size_t)k * DP];
        ws[PART_P + b * DP + t] = acc;
    } else {
        const int b = blockIdx.x - NC_P;
        const int base = b * 64;
        if (t < 64) {
            const float r = ws[R_S + sidx[base + t]];
            const float m = wmax64(r);
            const float e = expf(r - m);
            const float z = wsum64(e);
            wgt[t] = e;
            if (t == 0) { ws[CH_MS + b] = m; ws[CH_ZS + b] = z; }
        }
        __syncthreads();
        const int c = t & 127, half = t >> 7;
        float acc = 0.f;
        #pragma unroll 8
        for (int k = half * 32; k < half * 32 + 32; ++k)
            acc += wgt[k] * sn[(size_t)(base + k) * DS + c];
        red[t] = acc;
        __syncthreads();
        if (t < DS) ws[PART_S + b * DS + t] = red[t] + red[t + 128];
    }
}

// ---- kC: combine chunk stats/partials + tiny matvec chains (2 blocks) ----
__global__ __launch_bounds__(256)
void kC(const float* __restrict__ Wpp, const float* __restrict__ bpp,
        const float* __restrict__ Wsp, const float* __restrict__ bsp,
        const float* __restrict__ Wpo, const float* __restrict__ bpo,
        const float* __restrict__ Wso, const float* __restrict__ bso,
        float* __restrict__ ws) {
    __shared__ float e[256], red[256], mv[256], vv[128];
    const int t = threadIdx.x;
    if (blockIdx.x == 0) {      // prot chain: m_p -> v_p -> u_s
        const float* chM = ws + CH_MP;
        const float* chZ = ws + CH_ZP;
        red[t] = chM[t]; __syncthreads();
        for (int s = 128; s > 0; s >>= 1) { if (t < s) red[t] = fmaxf(red[t], red[t+s]); __syncthreads(); }
        const float M = red[0]; __syncthreads();
        const float sc = expf(chM[t] - M);
        red[t] = chZ[t] * sc; __syncthreads();
        for (int s = 128; s > 0; s >>= 1) { if (t < s) red[t] += red[t+s]; __syncthreads(); }
        const float invZ = 1.f / red[0];
        e[t] = sc * invZ;
        __syncthreads();
        {
            float acc = 0.f;
            #pragma unroll 8
            for (int b = 0; b < NC_P; ++b) acc += ws[PART_P + b * DP + t] * e[b];
            mv[t] = acc;
        }
        __syncthreads();
        if (t < DI) {
            float s = bpp[t];
            #pragma unroll 8
            for (int c = 0; c < DP; ++c) s += mv[c] * Wpp[c * DI + t];
            vv[t] = s;
        }
        __syncthreads();
        if (t < DS) {
            float s = bso[t];
            #pragma unroll 8
            for (int d = 0; d < DI; ++d) s += vv[d] * Wso[d * DS + t];
            ws[U_S + t] = s;
        }
    } else {                    // sub chain: m_s -> v_s -> u_p
        const float* chM = ws + CH_MS;
        const float* chZ = ws + CH_ZS;
        red[t] = (t < NC_S) ? chM[t] : -INFINITY; __syncthreads();
        for (int s = 128; s > 0; s >>= 1) { if (t < s) red[t] = fmaxf(red[t], red[t+s]); __syncthreads(); }
        const float M = red[0]; __syncthreads();
        const float sc = (t < NC_S) ? expf(chM[t] - M) : 0.f;
        red[t] = (t < NC_S) ? chZ[t] * sc : 0.f; __syncthreads();
        for (int s = 128; s > 0; s >>= 1) { if (t < s) red[t] += red[t+s]; __syncthreads(); }
        const float invZ = 1.f / red[0];
        if (t < NC_S) e[t] = sc * invZ;
        __syncthreads();
        if (t < DS) {
            float acc = 0.f;
            #pragma unroll 8
            for (int b = 0; b < NC_S; ++b) acc += ws[PART_S + b * DS + t] * e[b];
            mv[t] = acc;
        }
        __syncthreads();
        if (t < DI) {
            float s = bsp[t];
            #pragma unroll 8
            for (int c = 0; c < DS; ++c) s += mv[c] * Wsp[c * DI + t];
            vv[t] = s;
        }
        __syncthreads();
        {
            float s = bpo[t];
            #pragma unroll 8
            for (int d = 0; d < DI; ++d) s += vv[d] * Wpo[d * DP + t];
            ws[U_P + t] = s;
        }
    }
}

// ---- kD: finalize all four outputs (float4 grid-stride) ----
__global__ __launch_bounds__(256)
void kD(const float* __restrict__ pn, const float* __restrict__ sn,
        const int* __restrict__ pidx, const int* __restrict__ sidx,
        const float* __restrict__ ws, float* __restrict__ out) {
    __shared__ float up[DP];
    __shared__ float us[DS];
    const int t = threadIdx.x;
    up[t] = ws[U_P + t];
    if (t < DS) us[t] = ws[U_S + t];
    __syncthreads();
    for (int g4 = blockIdx.x * 256 + t; g4 < TOTAL4; g4 += gridDim.x * 256) {
        const int e4 = g4 * 4;
        float4 o;
        if (e4 < O1) {
            float4 x = *(const float4*)(pn + e4);
            int c = e4 & (DP - 1);
            o = make_float4(x.x + up[c], x.y + up[c+1], x.z + up[c+2], x.w + up[c+3]);
        } else if (e4 < O2) {
            int i = e4 - O1;
            int4 v = *(const int4*)(pidx + i);
            o = make_float4((float)v.x, (float)v.y, (float)v.z, (float)v.w);
        } else if (e4 < O3) {
            int i = e4 - O2;
            float4 x = *(const float4*)(sn + i);
            int c = i & (DS - 1);
            o = make_float4(x.x + us[c], x.y + us[c+1], x.z + us[c+2], x.w + us[c+3]);
        } else {
            int i = e4 - O3;
            int4 v = *(const int4*)(sidx + i);
            o = make_float4((float)v.x, (float)v.y, (float)v.z, (float)v.w);
        }
        *(float4*)(out + e4) = o;
    }
}

extern "C" void kernel_launch(void* const* d_in, const int* in_sizes, int n_in,
                              void* d_out, int out_size, void* d_ws, size_t ws_size,
                              hipStream_t stream) {
    const float* pn  = (const float*)d_in[0];
    const float* sn  = (const float*)d_in[1];
    const float* Wpp = (const float*)d_in[2];
    const float* bpp = (const float*)d_in[3];
    const float* Wsp = (const float*)d_in[4];
    const float* bsp = (const float*)d_in[5];
    const float* Wpo = (const float*)d_in[6];
    const float* bpo = (const float*)d_in[7];
    const float* Wso = (const float*)d_in[8];
    const float* bso = (const float*)d_in[9];
    const int* pidx  = (const int*)d_in[10];
    const int* sidx  = (const int*)d_in[11];
    float* ws  = (float*)d_ws;
    float* out = (float*)d_out;

    hipLaunchKernelGGL(kA, dim3(GA), dim3(256), 0, stream, pn, sn, Wpp, bpp, Wsp, bsp, ws);
    hipLaunchKernelGGL(kB, dim3(NC_P + NC_S), dim3(256), 0, stream, pn, sn, pidx, sidx, ws);
    hipLaunchKernelGGL(kC, dim3(2), dim3(256), 0, stream,
                       Wpp, bpp, Wsp, bsp, Wpo, bpo, Wso, bso, ws);
    hipLaunchKernelGGL(kD, dim3(2048), dim3(256), 0, stream, pn, sn, pidx, sidx, ws, out);
}